// Round 7
// baseline (2328.375 us; speedup 1.0000x reference)
//
#include <hip/hip_runtime.h>

typedef _Float16 f16;
typedef f16  f16x8 __attribute__((ext_vector_type(8)));
typedef f16  f16x4 __attribute__((ext_vector_type(4)));
typedef float f32x4 __attribute__((ext_vector_type(4)));

constexpr int NN = 150000;
constexpr int EE = 1200000;

// ------------------------------------------------------------------
// Generic MFMA f16 GEMM:  C = act( (A1*scale + A2) @ W^T + bias )
// W pre-laid in fragment-linear layout: frag[(ntile*KS+ks)*64+lane][8]
// A rows staged to LDS per 32-k chunk. Block=256 thr, 64 M-rows/block.
// blockIdx.y picks an 8-ntile (128-col) N-chunk: one staging pass per block.
// ------------------------------------------------------------------
template<class TA1, class TA2, class TC, int ACT>
__global__ __launch_bounds__(256) void k_gemm(
    const TA1* __restrict__ A1, int rsA1,
    const float* __restrict__ Ascale,
    const TA2* __restrict__ A2, int rsA2,
    const f16* __restrict__ W, const float* __restrict__ bias,
    TC* __restrict__ C, int rsC,
    int M, int K, int N, int KS, int NT)
{
  __shared__ f16x8 As8[256];
  const int tid  = threadIdx.x;
  const int lane = tid & 63, wave = tid >> 6;
  const int m0   = blockIdx.x * 64;
  const int sr   = tid >> 2, scb = tid & 3;
  const int grow = m0 + sr;
  const bool rv  = grow < M;
  const float sc = (Ascale && rv) ? Ascale[grow] : 1.0f;
  const f16x8* __restrict__ W8 = (const f16x8*)W;

  const int nc  = blockIdx.y << 3;
  if (nc >= NT) return;
  const int nth = (NT - nc) < 8 ? (NT - nc) : 8;
  f32x4 acc[8];
#pragma unroll
  for (int i = 0; i < 8; ++i) acc[i] = (f32x4){0.f, 0.f, 0.f, 0.f};
  for (int ks = 0; ks < KS; ++ks) {
    const int k0 = ks * 32 + scb * 8;
    f16x8 hv;
#pragma unroll
    for (int j = 0; j < 8; ++j) {
      float v = 0.f;
      int k = k0 + j;
      if (rv && k < K) {
        v = (float)A1[(size_t)grow * rsA1 + k] * sc;
        if (A2) v += (float)A2[(size_t)grow * rsA2 + k];
      }
      hv[j] = (f16)v;
    }
    As8[((sr >> 4) << 6) | (sr & 15) | (scb << 4)] = hv;
    __syncthreads();
    const f16x8 a = As8[(wave << 6) | lane];
#pragma unroll
    for (int nt = 0; nt < 8; ++nt) {
      if (nt < nth) {
        f16x8 b = W8[((size_t)(nc + nt) * KS + ks) * 64 + lane];
        acc[nt] = __builtin_amdgcn_mfma_f32_16x16x32_f16(a, b, acc[nt], 0, 0, 0);
      }
    }
    __syncthreads();
  }
  const int colb  = (nc << 4) + (lane & 15);
  const int rbase = m0 + (wave << 4) + ((lane >> 4) << 2);
#pragma unroll
  for (int nt = 0; nt < 8; ++nt) {
    if (nt < nth) {
      int col = colb + (nt << 4);
      if (col < N) {
        float bb = bias ? bias[col] : 0.f;
#pragma unroll
        for (int j = 0; j < 4; ++j) {
          int r = rbase + j;
          if (r < M) {
            float v = acc[nt][j] + bb;
            if (ACT == 1) v = fmaxf(v, 0.f);
            else if (ACT == 2) v = tanhf(v);
            C[(size_t)r * rsC + col] = (TC)v;
          }
        }
      }
    }
  }
}

// ------------------------------------------------------------------
// gin2 + fused max/mean pooling, LDS-free A path.
// Input SUM = H1 + agg (f16, (N,168), both views) precomputed by k_gather2.
// Each lane loads its MFMA A-fragment (8 contiguous f16 of one row)
// directly from global via two guarded f16x4 loads (84 = 21 quads exact).
// blockIdx.y = column chunk (27/26 of 53 ntiles). No __syncthreads in loop.
// Rows >=375 of a quarter read in-workspace garbage; their C rows are
// rem-masked before pooling (MFMA is row-wise), so results are exact.
// ------------------------------------------------------------------
__global__ __launch_bounds__(256) void k_gin2pool(
    const f16* __restrict__ SUM,
    const f16* __restrict__ W, const float* __restrict__ bias,
    float* __restrict__ PP)
{
  __shared__ float Red[4][27][2][16];
  const int blk = blockIdx.x;
  const int cc  = blockIdx.y;                 // column chunk 0..1
  const int ntBase = cc * 27;
  const int ntc = cc ? 26 : 27;
  const int v = blk / 400;
  const int g = (blk / 4) % 100;
  const int p = blk & 3;
  const int nodeBeg = g * 1500 + p * 375;
  const int tid = threadIdx.x, lane = tid & 63, wave = tid >> 6;
  const int voff = v * 84;
  const f16x8* __restrict__ W8 = (const f16x8*)W;
  const int rloc = (wave << 4) + ((lane >> 4) << 2);
  const int arow = (wave << 4) + (lane & 15);
  const int kgrp = (lane >> 4) << 3;          // 0,8,16,24
  float mx[27], sm[27];
#pragma unroll
  for (int i = 0; i < 27; ++i) { mx[i] = 0.f; sm[i] = 0.f; }

  for (int ch = 0; ch < 6; ++ch) {
    const int lr = ch * 64 + arow;
    const f16* rp = SUM + (size_t)(nodeBeg + lr) * 168 + voff;
    f16x8 a[3];
#pragma unroll
    for (int ks = 0; ks < 3; ++ks) {
      const int kb = ks * 32 + kgrp;          // 0..88, multiple of 8
      f16x4 lo = (kb     < 84) ? *(const f16x4*)(rp + kb)     : (f16x4){0,0,0,0};
      f16x4 hi = (kb + 4 < 84) ? *(const f16x4*)(rp + kb + 4) : (f16x4){0,0,0,0};
      f16x8 av;
      av[0]=lo[0]; av[1]=lo[1]; av[2]=lo[2]; av[3]=lo[3];
      av[4]=hi[0]; av[5]=hi[1]; av[6]=hi[2]; av[7]=hi[3];
      a[ks] = av;
    }
    const int rem = 375 - (ch * 64 + rloc);   // #valid rows among this lane's 4
#pragma unroll
    for (int nt = 0; nt < 27; ++nt) {
      if (nt < ntc) {
        const int ntg = ntBase + nt;
        f32x4 acc = (f32x4){0.f, 0.f, 0.f, 0.f};
        acc = __builtin_amdgcn_mfma_f32_16x16x32_f16(a[0], W8[(ntg * 3 + 0) * 64 + lane], acc, 0, 0, 0);
        acc = __builtin_amdgcn_mfma_f32_16x16x32_f16(a[1], W8[(ntg * 3 + 1) * 64 + lane], acc, 0, 0, 0);
        acc = __builtin_amdgcn_mfma_f32_16x16x32_f16(a[2], W8[(ntg * 3 + 2) * 64 + lane], acc, 0, 0, 0);
        const int col = (ntg << 4) + (lane & 15);
        const float bb = (col < 840) ? bias[col] : 0.f;
#pragma unroll
        for (int j = 0; j < 4; ++j) {
          float r = fmaxf(acc[j] + bb, 0.f);   // relu
          if (j >= rem) r = 0.f;               // mask padded rows
          mx[nt] = fmaxf(mx[nt], r);
          sm[nt] += r;
        }
      }
    }
  }
#pragma unroll
  for (int nt = 0; nt < 27; ++nt) {
    if (nt < ntc) {
      float m = mx[nt], s = sm[nt];
      m = fmaxf(m, __shfl_xor(m, 16)); s += __shfl_xor(s, 16);
      m = fmaxf(m, __shfl_xor(m, 32)); s += __shfl_xor(s, 32);
      if (lane < 16) { Red[wave][nt][0][lane] = m; Red[wave][nt][1][lane] = s; }
    }
  }
  __syncthreads();
  const size_t base = (size_t)blk * 1696 + ((size_t)ntBase << 4);
  for (int u = tid; u < ntc * 16; u += 256) {
    int nt = u >> 4, c = u & 15;
    float m = fmaxf(fmaxf(Red[0][nt][0][c], Red[1][nt][0][c]),
                    fmaxf(Red[2][nt][0][c], Red[3][nt][0][c]));
    float s = Red[0][nt][1][c] + Red[1][nt][1][c] + Red[2][nt][1][c] + Red[3][nt][1][c];
    PP[base + u]       = m;
    PP[base + 848 + u] = s;
  }
}

// ---------------- CSR build ----------------
__global__ void k_hist(const int* __restrict__ dst, int* __restrict__ deg) {
  int i = blockIdx.x * 256 + threadIdx.x;
  if (i < EE) atomicAdd(&deg[dst[i]], 1);
}
__global__ __launch_bounds__(256) void k_scan1(const int* __restrict__ deg, int* __restrict__ bsum) {
  __shared__ int sh[256];
  int base = blockIdx.x * 2048 + threadIdx.x * 8;
  int s = 0;
#pragma unroll
  for (int j = 0; j < 8; ++j) { int idx = base + j; if (idx < NN) s += deg[idx]; }
  sh[threadIdx.x] = s; __syncthreads();
  for (int d = 128; d; d >>= 1) { if (threadIdx.x < d) sh[threadIdx.x] += sh[threadIdx.x + d]; __syncthreads(); }
  if (threadIdx.x == 0) bsum[blockIdx.x] = sh[0];
}
__global__ void k_scan2(int* __restrict__ bsum, int nb) {
  if (threadIdx.x == 0 && blockIdx.x == 0) {
    int run = 0;
    for (int i = 0; i < nb; ++i) { int t = bsum[i]; bsum[i] = run; run += t; }
  }
}
__global__ __launch_bounds__(256) void k_scan3(const int* __restrict__ deg, const int* __restrict__ bsum,
                                               int* __restrict__ rowp, int* __restrict__ curs) {
  __shared__ int sh[256];
  int t = threadIdx.x;
  int base = blockIdx.x * 2048 + t * 8;
  int vals[8]; int tot = 0;
#pragma unroll
  for (int j = 0; j < 8; ++j) { int idx = base + j; vals[j] = (idx < NN) ? deg[idx] : 0; tot += vals[j]; }
  sh[t] = tot; __syncthreads();
  for (int d = 1; d < 256; d <<= 1) {
    int v = (t >= d) ? sh[t - d] : 0; __syncthreads();
    sh[t] += v; __syncthreads();
  }
  int run = bsum[blockIdx.x] + sh[t] - tot;
#pragma unroll
  for (int j = 0; j < 8; ++j) {
    int idx = base + j;
    if (idx < NN) {
      rowp[idx] = run; curs[idx] = run; run += vals[j];
      if (idx == NN - 1) rowp[NN] = run;
    }
  }
}
__global__ void k_fill(const int* __restrict__ src, const int* __restrict__ dst,
                       int* __restrict__ curs, int* __restrict__ cols) {
  int i = blockIdx.x * 256 + threadIdx.x;
  if (i < EE) { int pp = atomicAdd(&curs[dst[i]], 1); cols[pp] = src[i]; }
}

// ---------------- gathers (wave per node, CSR) ----------------
__global__ __launch_bounds__(256) void k_gather1(
    const float* __restrict__ x, const float* __restrict__ mask,
    const int* __restrict__ rowp, const int* __restrict__ cols,
    f16* __restrict__ AGG)
{
  int gw = (blockIdx.x * 256 + threadIdx.x) >> 6;
  int lane = threadIdx.x & 63;
  if (gw >= NN) return;
  int beg = rowp[gw], end = rowp[gw + 1];
  float ax0 = 0, ax1 = 0, ax2 = 0, ax3 = 0, ay0 = 0, ay1 = 0, ay2 = 0, ay3 = 0;
  bool act = lane < 21;
  for (int e = beg; e < end; ++e) {
    int s = cols[e];
    if (act) {
      float4 xv = ((const float4*)(x + (size_t)s * 84))[lane];
      float m = mask[s];
      ax0 += xv.x; ax1 += xv.y; ax2 += xv.z; ax3 += xv.w;
      ay0 += xv.x * m; ay1 += xv.y * m; ay2 += xv.z * m; ay3 += xv.w * m;
    }
  }
  if (act) {
    f16x4 hx = {(f16)ax0, (f16)ax1, (f16)ax2, (f16)ax3};
    f16x4 hy = {(f16)ay0, (f16)ay1, (f16)ay2, (f16)ay3};
    ((f16x4*)(AGG + (size_t)gw * 168))[lane] = hx;
    ((f16x4*)(AGG + (size_t)gw * 168 + 84))[lane] = hy;
  }
}
// SUM[gw] = H1[gw] + sum_{nbr} H1[nbr]  (both views interleaved, f16)
__global__ __launch_bounds__(256) void k_gather2(
    const f16* __restrict__ H1, const int* __restrict__ rowp, const int* __restrict__ cols,
    f16* __restrict__ SUM)
{
  int gw = (blockIdx.x * 256 + threadIdx.x) >> 6;
  int lane = threadIdx.x & 63;
  if (gw >= NN) return;
  int beg = rowp[gw], end = rowp[gw + 1];
  float acc[8] = {0, 0, 0, 0, 0, 0, 0, 0};
  bool act = lane < 21;
  if (act) {
    f16x8 own = ((const f16x8*)(H1 + (size_t)gw * 168))[lane];
#pragma unroll
    for (int j = 0; j < 8; ++j) acc[j] = (float)own[j];
  }
  for (int e = beg; e < end; ++e) {
    int s = cols[e];
    if (act) {
      f16x8 vv = ((const f16x8*)(H1 + (size_t)s * 168))[lane];
#pragma unroll
      for (int j = 0; j < 8; ++j) acc[j] += (float)vv[j];
    }
  }
  if (act) {
    f16x8 h;
#pragma unroll
    for (int j = 0; j < 8; ++j) h[j] = (f16)acc[j];
    ((f16x8*)(SUM + (size_t)gw * 168))[lane] = h;
  }
}

// ---------------- GRU (block per (dir, batch-row); Wh in regs) ----------------
__global__ __launch_bounds__(320) void k_gru(
    const float* __restrict__ GIf, const float* __restrict__ GIb,
    const float* __restrict__ whf, const float* __restrict__ whb,
    const float* __restrict__ bhf, const float* __restrict__ bhb,
    float* __restrict__ S)
{
  __shared__ __align__(16) float hL[100];
  __shared__ float ghL[300];
  const int blk = blockIdx.x;
  const int dir = blk / 100, b = blk % 100;
  const float* GI = dir ? GIb : GIf;
  const float* wh = dir ? whb : whf;
  const float* bh = dir ? bhb : bhf;
  const int t = threadIdx.x;
  float4 wr[25];
  float bhr = 0.f;
  if (t < 300) {
#pragma unroll
    for (int kb = 0; kb < 25; ++kb) wr[kb] = ((const float4*)(wh + (size_t)t * 100))[kb];
    bhr = bh[t];
  }
  if (t < 100) hL[t] = 0.f;
  __syncthreads();
  for (int step = 0; step < 100; ++step) {
    int tt = dir ? (99 - step) : step;
    if (t < 300) {
      float p0 = 0.f, p1 = 0.f, p2 = 0.f, p3 = 0.f;
#pragma unroll
      for (int kb = 0; kb < 25; ++kb) {
        float4 h4 = *(const float4*)&hL[kb * 4];
        p0 += wr[kb].x * h4.x; p1 += wr[kb].y * h4.y;
        p2 += wr[kb].z * h4.z; p3 += wr[kb].w * h4.w;
      }
      ghL[t] = bhr + (p0 + p1) + (p2 + p3);
    }
    __syncthreads();
    if (t < 100) {
      const float* gi = GI + ((size_t)tt * 100 + b) * 300;
      float r = 1.f / (1.f + __expf(-(gi[t] + ghL[t])));
      float z = 1.f / (1.f + __expf(-(gi[100 + t] + ghL[100 + t])));
      float n = tanhf(gi[200 + t] + r * ghL[200 + t]);
      float h = (1.f - z) * n + z * hL[t];
      hL[t] = h;
      S[((size_t)tt * 100 + b) * 200 + dir * 100 + t] = fmaxf(h, 0.f);
    }
    __syncthreads();
  }
}

// ---------------- attention softmax (over batch axis) + wsum ----------------
__global__ __launch_bounds__(256) void k_soft(const float* __restrict__ ATT2, float* __restrict__ wsum) {
  __shared__ float mL[256], dL[256];
  const int t = blockIdx.x, c = threadIdx.x;
  const float* A = ATT2 + (size_t)t * 100 * 256;
  float m = -1e30f;
  for (int b = 0; b < 100; ++b) m = fmaxf(m, A[b * 256 + c]);
  float den = 0.f;
  for (int b = 0; b < 100; ++b) den += __expf(A[b * 256 + c] - m);
  mL[c] = m; dL[c] = 1.f / den;
  __syncthreads();
  if (c < 100) {
    float acc = 0.f;
    const float* Ar = A + c * 256;
    for (int k = 0; k < 256; ++k) acc += __expf(Ar[k] - mL[k]) * dL[k];
    wsum[t * 100 + c] = acc;
  }
}
__global__ __launch_bounds__(256) void k_smi(const float* __restrict__ S, const float* __restrict__ wsum,
                                             float* __restrict__ SMI0) {
  const int t = blockIdx.x, c = threadIdx.x;
  if (c < 200) {
    float acc = 0.f;
    for (int b = 0; b < 100; ++b) acc += wsum[t * 100 + b] * S[((size_t)t * 100 + b) * 200 + c];
    SMI0[t * 200 + c] = acc * 0.1f;
  }
}

// ---------------- pool partial reduce (graph size fixed at 1500 nodes) ----------------
__global__ void k_poolred(const float* __restrict__ PP, float* __restrict__ POOL) {
  int i = blockIdx.x * 256 + threadIdx.x;
  if (i >= 2 * 100 * 848) return;
  int v = i / (100 * 848); int r = i % (100 * 848); int g = r / 848; int col = r % 848;
  if (col >= 840) return;
  size_t b0 = (size_t)((v * 100 + g) * 4) * 1696;
  float m = 0.f, s = 0.f;
#pragma unroll
  for (int p = 0; p < 4; ++p) {
    m = fmaxf(m, PP[b0 + (size_t)p * 1696 + col]);
    s += PP[b0 + (size_t)p * 1696 + 848 + col];
  }
  POOL[(size_t)(v * 100 + g) * 1696 + col] = m;
  POOL[(size_t)(v * 100 + g) * 1696 + 840 + col] = s * (1.0f / 1500.0f);
}

// ---------------- misc ----------------
__global__ void k_concat(const float* __restrict__ out, const float* __restrict__ SMI, float* __restrict__ FFIN) {
  int i = blockIdx.x * 256 + threadIdx.x;
  if (i < 100 * 768) {
    int g = i / 768, c = i % 768;
    FFIN[i] = (c < 512) ? out[100 + g * 512 + c] : SMI[g * 256 + (c - 512)];
  }
}
__global__ __launch_bounds__(256) void k_z(const float* __restrict__ FFH, const float* __restrict__ w2,
                                           const float* __restrict__ b2, float* __restrict__ out) {
  __shared__ float part[4];
  const int g = blockIdx.x, t = threadIdx.x;
  float v = FFH[g * 256 + t] * w2[t];
  for (int o = 32; o; o >>= 1) v += __shfl_down(v, o);
  if ((t & 63) == 0) part[t >> 6] = v;
  __syncthreads();
  if (t == 0) out[g] = part[0] + part[1] + part[2] + part[3] + b2[0];
}

// ---------------- weight -> f16 fragment layout prep ----------------
struct PrepArgs {
  const float* src[11];
  f16x8* dst[11];
  int Nw[11], Kw[11], KS[11];
  int slot0[12];
};
__global__ __launch_bounds__(256) void k_prep(PrepArgs pa) {
  int s = blockIdx.x * 256 + threadIdx.x;
  if (s >= pa.slot0[11]) return;
  int wi = 0;
  while (s >= pa.slot0[wi + 1]) ++wi;
  int loc = s - pa.slot0[wi];
  int KS = pa.KS[wi];
  int nt = loc / (KS * 64);
  int rem = loc - nt * KS * 64;
  int ks = rem >> 6, lane = rem & 63;
  int col = (nt << 4) + (lane & 15);
  int kb = ks * 32 + ((lane >> 4) << 3);
  const float* src = pa.src[wi];
  int Nw = pa.Nw[wi], Kw = pa.Kw[wi];
  f16x8 hv;
#pragma unroll
  for (int j = 0; j < 8; ++j) {
    int k = kb + j;
    float v = (col < Nw && k < Kw) ? src[(size_t)col * Kw + k] : 0.f;
    hv[j] = (f16)v;
  }
  pa.dst[wi][loc] = hv;
}

// ==================================================================
extern "C" void kernel_launch(void* const* d_in, const int* in_sizes, int n_in,
                              void* d_out, int out_size, void* d_ws, size_t ws_size,
                              hipStream_t stream) {
  (void)in_sizes; (void)n_in; (void)out_size;
  const float* x      = (const float*)d_in[0];
  const float* smi_em = (const float*)d_in[1];
  const float* mask   = (const float*)d_in[2];
  const int*   eidx   = (const int*)d_in[3];
  const float* wi_f   = (const float*)d_in[5];
  const float* wh_f   = (const float*)d_in[6];
  const float* bi_f   = (const float*)d_in[7];
  const float* bh_f   = (const float*)d_in[8];
  const float* wi_b   = (const float*)d_in[9];
  const float* wh_b   = (const float*)d_in[10];
  const float* bi_b   = (const float*)d_in[11];
  const float* bh_b   = (const float*)d_in[12];
  const float* fc_w1  = (const float*)d_in[13];
  const float* fc_b1  = (const float*)d_in[14];
  const float* fc_w2  = (const float*)d_in[15];
  const float* fc_b2  = (const float*)d_in[16];
  const float* lin_w1 = (const float*)d_in[17];
  const float* lin_b1 = (const float*)d_in[18];
  const float* lin_w2 = (const float*)d_in[19];
  const float* lin_b2 = (const float*)d_in[20];
  const float* conv1_w= (const float*)d_in[21];
  const float* conv1_b= (const float*)d_in[22];
  const float* conv2_w= (const float*)d_in[23];
  const float* conv2_b= (const float*)d_in[24];
  const float* fcg_w1 = (const float*)d_in[25];
  const float* fcg_b1 = (const float*)d_in[26];
  const float* fcg_w2 = (const float*)d_in[27];
  const float* fcg_b2 = (const float*)d_in[28];
  const float* ff_w1  = (const float*)d_in[29];
  const float* ff_b1  = (const float*)d_in[30];
  const float* ff_w2  = (const float*)d_in[31];
  const float* ff_b2  = (const float*)d_in[32];
  float* out = (float*)d_out;

  char* wsb = (char*)d_ws;
  size_t off = 0;
  auto alloc = [&](size_t bytes) -> void* {
    void* p = wsb + off;
    off += (bytes + 255) & ~(size_t)255;
    return p;
  };

  // weight frag buffers
  struct WDesc { const float* src; int Nw, Kw; };
  const WDesc WL[11] = {
    {wi_f, 300, 100}, {wi_b, 300, 100}, {fc_w1, 512, 200}, {fc_w2, 256, 512},
    {lin_w1, 512, 200}, {lin_w2, 256, 512}, {conv1_w, 84, 84}, {conv2_w, 840, 84},
    {fcg_w1, 1024, 1680}, {fcg_w2, 512, 1024}, {ff_w1, 256, 768}};
  PrepArgs pa;
  f16* Wb[11];
  int s0 = 0;
  for (int i = 0; i < 11; ++i) {
    int NT = (WL[i].Nw + 15) / 16, KS = (WL[i].Kw + 31) / 32;
    int slots = NT * KS * 64;
    Wb[i] = (f16*)alloc((size_t)slots * 16);
    pa.src[i] = WL[i].src; pa.dst[i] = (f16x8*)Wb[i];
    pa.Nw[i] = WL[i].Nw; pa.Kw[i] = WL[i].Kw; pa.KS[i] = KS;
    pa.slot0[i] = s0; s0 += slots;
  }
  pa.slot0[11] = s0;

  float* WSUM = (float*)alloc(10000 * 4);
  float* SMI0 = (float*)alloc(100 * 200 * 4);
  float* SMIH = (float*)alloc(100 * 512 * 4);
  float* SMI  = (float*)alloc(100 * 256 * 4);
  int* DEG  = (int*)alloc((size_t)NN * 4);
  int* ROWP = (int*)alloc((size_t)(NN + 1) * 4);
  int* CURS = (int*)alloc((size_t)NN * 4);
  int* COLS = (int*)alloc((size_t)EE * 4);
  int* BSUM = (int*)alloc(1024);
  float* PP   = (float*)alloc((size_t)800 * 1696 * 4);
  float* POOL = (float*)alloc((size_t)200 * 1696 * 4);
  float* FCGH = (float*)alloc((size_t)200 * 1024 * 4);
  float* FFIN = (float*)alloc(100 * 768 * 4);
  float* FFH  = (float*)alloc(100 * 256 * 4);
  // big overlapped region: SMILES buffers (phase 1) / graph buffers (phase 2)
  char* R = (char*)alloc(100800000);
  f16* AGG = (f16*)R;                    // gin1 aggregate, later reused as SUM
  f16* H1  = (f16*)(R + 50400000);
  f16* SUM = AGG;                        // gather2 output (AGG is dead by then)
  float* GIf  = (float*)R;
  float* GIb  = (float*)(R + 12000000);
  float* S    = (float*)(R + 24000000);
  float* ATT1 = (float*)(R + 32000000);
  float* ATT2 = (float*)(R + 52480000);
  if (ws_size < off) return;  // workspace too small: bail (will fail validation loudly)

  const int* esrc = eidx;
  const int* edst = eidx + EE;
  const float* FNULL = nullptr;

  // ---- weight prep ----
  k_prep<<<(s0 + 255) / 256, 256, 0, stream>>>(pa);

  // ---- SMILES branch ----
  k_gemm<float, float, float, 0><<<dim3(157, 3), 256, 0, stream>>>(smi_em, 100, nullptr, FNULL, 0, Wb[0], bi_f, GIf, 300, 10000, 100, 300, 4, 19);
  k_gemm<float, float, float, 0><<<dim3(157, 3), 256, 0, stream>>>(smi_em, 100, nullptr, FNULL, 0, Wb[1], bi_b, GIb, 300, 10000, 100, 300, 4, 19);
  k_gru<<<200, 320, 0, stream>>>(GIf, GIb, wh_f, wh_b, bh_f, bh_b, S);
  k_gemm<float, float, float, 1><<<dim3(157, 4), 256, 0, stream>>>(S, 200, nullptr, FNULL, 0, Wb[2], fc_b1, ATT1, 512, 10000, 200, 512, 7, 32);
  k_gemm<float, float, float, 2><<<dim3(157, 2), 256, 0, stream>>>(ATT1, 512, nullptr, FNULL, 0, Wb[3], fc_b2, ATT2, 256, 10000, 512, 256, 16, 16);
  k_soft<<<100, 256, 0, stream>>>(ATT2, WSUM);
  k_smi<<<100, 256, 0, stream>>>(S, WSUM, SMI0);
  k_gemm<float, float, float, 0><<<dim3(2, 4), 256, 0, stream>>>(SMI0, 200, nullptr, FNULL, 0, Wb[4], lin_b1, SMIH, 512, 100, 200, 512, 7, 32);
  k_gemm<float, float, float, 0><<<dim3(2, 2), 256, 0, stream>>>(SMIH, 512, nullptr, FNULL, 0, Wb[5], lin_b2, SMI, 256, 100, 512, 256, 16, 16);

  // ---- graph branch: CSR ----
  hipMemsetAsync(DEG, 0, (size_t)NN * 4, stream);
  k_hist<<<(EE + 255) / 256, 256, 0, stream>>>(edst, DEG);
  k_scan1<<<74, 256, 0, stream>>>(DEG, BSUM);
  k_scan2<<<1, 64, 0, stream>>>(BSUM, 74);
  k_scan3<<<74, 256, 0, stream>>>(DEG, BSUM, ROWP, CURS);
  k_fill<<<(EE + 255) / 256, 256, 0, stream>>>(esrc, edst, CURS, COLS);

  // ---- gin1 ----
  k_gather1<<<NN / 4, 256, 0, stream>>>(x, mask, ROWP, COLS, AGG);
  k_gemm<float, f16, f16, 1><<<dim3(2344, 1), 256, 0, stream>>>(x, 84, nullptr, (const f16*)AGG, 168, Wb[6], conv1_b, H1, 168, NN, 84, 84, 3, 6);
  k_gemm<float, f16, f16, 1><<<dim3(2344, 1), 256, 0, stream>>>(x, 84, mask, (const f16*)(AGG + 84), 168, Wb[6], conv1_b, H1 + 84, 168, NN, 84, 84, 3, 6);

  // ---- gin2 + pooling ----
  k_gather2<<<NN / 4, 256, 0, stream>>>(H1, ROWP, COLS, SUM);
  k_gin2pool<<<dim3(800, 2), 256, 0, stream>>>(SUM, Wb[7], conv2_b, PP);
  k_poolred<<<(2 * 100 * 848 + 255) / 256, 256, 0, stream>>>(PP, POOL);

  // ---- fcg MLP (both views at once: M=200; writes x_g then y_g into d_out) ----
  k_gemm<float, float, float, 1><<<dim3(4, 8), 256, 0, stream>>>(POOL, 1696, nullptr, FNULL, 0, Wb[8], fcg_b1, FCGH, 1024, 200, 1680, 1024, 53, 64);
  k_gemm<float, float, float, 0><<<dim3(4, 4), 256, 0, stream>>>(FCGH, 1024, nullptr, FNULL, 0, Wb[9], fcg_b2, out + 100, 512, 200, 1024, 512, 32, 32);

  // ---- final head ----
  k_concat<<<300, 256, 0, stream>>>(out, SMI, FFIN);
  k_gemm<float, float, float, 1><<<dim3(2, 2), 256, 0, stream>>>(FFIN, 768, nullptr, FNULL, 0, Wb[10], ff_b1, FFH, 256, 100, 768, 256, 24, 16);
  k_z<<<100, 256, 0, stream>>>(FFH, ff_w2, ff_b2, out);
}

// Round 9
// 1741.057 us; speedup vs baseline: 1.3373x; 1.3373x over previous
//
#include <hip/hip_runtime.h>

typedef _Float16 f16;
typedef f16  f16x8 __attribute__((ext_vector_type(8)));
typedef f16  f16x4 __attribute__((ext_vector_type(4)));
typedef float f32x4 __attribute__((ext_vector_type(4)));

constexpr int NN = 150000;
constexpr int EE = 1200000;

// ------------------------------------------------------------------
// Generic MFMA f16 GEMM:  C = act( (A1*scale + A2) @ W^T + bias )
// W pre-laid in fragment-linear layout: frag[(ntile*KS+ks)*64+lane][8]
// A rows staged to LDS per 32-k chunk. Block=256 thr, 64 M-rows/block.
// blockIdx.y picks an 8-ntile (128-col) N-chunk: one staging pass per block.
// ------------------------------------------------------------------
template<class TA1, class TA2, class TC, int ACT>
__global__ __launch_bounds__(256) void k_gemm(
    const TA1* __restrict__ A1, int rsA1,
    const float* __restrict__ Ascale,
    const TA2* __restrict__ A2, int rsA2,
    const f16* __restrict__ W, const float* __restrict__ bias,
    TC* __restrict__ C, int rsC,
    int M, int K, int N, int KS, int NT)
{
  __shared__ f16x8 As8[256];
  const int tid  = threadIdx.x;
  const int lane = tid & 63, wave = tid >> 6;
  const int m0   = blockIdx.x * 64;
  const int sr   = tid >> 2, scb = tid & 3;
  const int grow = m0 + sr;
  const bool rv  = grow < M;
  const float sc = (Ascale && rv) ? Ascale[grow] : 1.0f;
  const f16x8* __restrict__ W8 = (const f16x8*)W;

  const int nc  = blockIdx.y << 3;
  if (nc >= NT) return;
  const int nth = (NT - nc) < 8 ? (NT - nc) : 8;
  f32x4 acc[8];
#pragma unroll
  for (int i = 0; i < 8; ++i) acc[i] = (f32x4){0.f, 0.f, 0.f, 0.f};
  for (int ks = 0; ks < KS; ++ks) {
    const int k0 = ks * 32 + scb * 8;
    f16x8 hv;
#pragma unroll
    for (int j = 0; j < 8; ++j) {
      float v = 0.f;
      int k = k0 + j;
      if (rv && k < K) {
        v = (float)A1[(size_t)grow * rsA1 + k] * sc;
        if (A2) v += (float)A2[(size_t)grow * rsA2 + k];
      }
      hv[j] = (f16)v;
    }
    As8[((sr >> 4) << 6) | (sr & 15) | (scb << 4)] = hv;
    __syncthreads();
    const f16x8 a = As8[(wave << 6) | lane];
#pragma unroll
    for (int nt = 0; nt < 8; ++nt) {
      if (nt < nth) {
        f16x8 b = W8[((size_t)(nc + nt) * KS + ks) * 64 + lane];
        acc[nt] = __builtin_amdgcn_mfma_f32_16x16x32_f16(a, b, acc[nt], 0, 0, 0);
      }
    }
    __syncthreads();
  }
  const int colb  = (nc << 4) + (lane & 15);
  const int rbase = m0 + (wave << 4) + ((lane >> 4) << 2);
#pragma unroll
  for (int nt = 0; nt < 8; ++nt) {
    if (nt < nth) {
      int col = colb + (nt << 4);
      if (col < N) {
        float bb = bias ? bias[col] : 0.f;
#pragma unroll
        for (int j = 0; j < 4; ++j) {
          int r = rbase + j;
          if (r < M) {
            float v = acc[nt][j] + bb;
            if (ACT == 1) v = fmaxf(v, 0.f);
            else if (ACT == 2) v = tanhf(v);
            C[(size_t)r * rsC + col] = (TC)v;
          }
        }
      }
    }
  }
}

// ------------------------------------------------------------------
// gin2 + fused max/mean pooling, LDS-free A path, 4 column chunks.
// Input SUM = H1 + agg (f16, (N,168), both views) precomputed by k_gather2.
// Each lane loads its MFMA A-fragment (8 contiguous f16 of one row)
// directly from global via two guarded f16x4 loads (84 = 21 quads exact).
// blockIdx.y = column chunk (14/14/14/11 of 53 ntiles) -> 28 acc VGPRs,
// no spill. No __syncthreads in the main loop.
// Rows >=375 of a quarter read in-workspace garbage; their C rows are
// rem-masked before pooling (MFMA is row-wise), so results are exact.
// ------------------------------------------------------------------
__global__ __launch_bounds__(256) void k_gin2pool(
    const f16* __restrict__ SUM,
    const f16* __restrict__ W, const float* __restrict__ bias,
    float* __restrict__ PP)
{
  __shared__ float Red[4][14][2][16];
  const int blk = blockIdx.x;
  const int cc  = blockIdx.y;                 // column chunk 0..3
  const int ntBase = cc * 14;
  const int ntc = (cc < 3) ? 14 : 11;
  const int v = blk / 400;
  const int g = (blk / 4) % 100;
  const int p = blk & 3;
  const int nodeBeg = g * 1500 + p * 375;
  const int tid = threadIdx.x, lane = tid & 63, wave = tid >> 6;
  const int voff = v * 84;
  const f16x8* __restrict__ W8 = (const f16x8*)W;
  const int rloc = (wave << 4) + ((lane >> 4) << 2);
  const int arow = (wave << 4) + (lane & 15);
  const int kgrp = (lane >> 4) << 3;          // 0,8,16,24
  float mx[14], sm[14];
#pragma unroll
  for (int i = 0; i < 14; ++i) { mx[i] = 0.f; sm[i] = 0.f; }

  for (int ch = 0; ch < 6; ++ch) {
    const int lr = ch * 64 + arow;
    const f16* rp = SUM + (size_t)(nodeBeg + lr) * 168 + voff;
    f16x8 a[3];
#pragma unroll
    for (int ks = 0; ks < 3; ++ks) {
      const int kb = ks * 32 + kgrp;          // 0..88, multiple of 8
      f16x4 lo = (kb     < 84) ? *(const f16x4*)(rp + kb)     : (f16x4){0,0,0,0};
      f16x4 hi = (kb + 4 < 84) ? *(const f16x4*)(rp + kb + 4) : (f16x4){0,0,0,0};
      f16x8 av;
      av[0]=lo[0]; av[1]=lo[1]; av[2]=lo[2]; av[3]=lo[3];
      av[4]=hi[0]; av[5]=hi[1]; av[6]=hi[2]; av[7]=hi[3];
      a[ks] = av;
    }
    const int rem = 375 - (ch * 64 + rloc);   // #valid rows among this lane's 4
#pragma unroll
    for (int nt = 0; nt < 14; ++nt) {
      if (nt < ntc) {
        const int ntg = ntBase + nt;
        f32x4 acc = (f32x4){0.f, 0.f, 0.f, 0.f};
        acc = __builtin_amdgcn_mfma_f32_16x16x32_f16(a[0], W8[(ntg * 3 + 0) * 64 + lane], acc, 0, 0, 0);
        acc = __builtin_amdgcn_mfma_f32_16x16x32_f16(a[1], W8[(ntg * 3 + 1) * 64 + lane], acc, 0, 0, 0);
        acc = __builtin_amdgcn_mfma_f32_16x16x32_f16(a[2], W8[(ntg * 3 + 2) * 64 + lane], acc, 0, 0, 0);
        const int col = (ntg << 4) + (lane & 15);
        const float bb = (col < 840) ? bias[col] : 0.f;
#pragma unroll
        for (int j = 0; j < 4; ++j) {
          float r = fmaxf(acc[j] + bb, 0.f);   // relu
          if (j >= rem) r = 0.f;               // mask padded rows
          mx[nt] = fmaxf(mx[nt], r);
          sm[nt] += r;
        }
      }
    }
  }
#pragma unroll
  for (int nt = 0; nt < 14; ++nt) {
    if (nt < ntc) {
      float m = mx[nt], s = sm[nt];
      m = fmaxf(m, __shfl_xor(m, 16)); s += __shfl_xor(s, 16);
      m = fmaxf(m, __shfl_xor(m, 32)); s += __shfl_xor(s, 32);
      if (lane < 16) { Red[wave][nt][0][lane] = m; Red[wave][nt][1][lane] = s; }
    }
  }
  __syncthreads();
  const size_t base = (size_t)blk * 1696 + ((size_t)ntBase << 4);
  for (int u = tid; u < ntc * 16; u += 256) {
    int nt = u >> 4, c = u & 15;
    float m = fmaxf(fmaxf(Red[0][nt][0][c], Red[1][nt][0][c]),
                    fmaxf(Red[2][nt][0][c], Red[3][nt][0][c]));
    float s = Red[0][nt][1][c] + Red[1][nt][1][c] + Red[2][nt][1][c] + Red[3][nt][1][c];
    PP[base + u]       = m;
    PP[base + 848 + u] = s;
  }
}

// ---------------- CSR build ----------------
__global__ void k_hist(const int* __restrict__ dst, int* __restrict__ deg) {
  int i = blockIdx.x * 256 + threadIdx.x;
  if (i < EE) atomicAdd(&deg[dst[i]], 1);
}
__global__ __launch_bounds__(256) void k_scan1(const int* __restrict__ deg, int* __restrict__ bsum) {
  __shared__ int sh[256];
  int base = blockIdx.x * 2048 + threadIdx.x * 8;
  int s = 0;
#pragma unroll
  for (int j = 0; j < 8; ++j) { int idx = base + j; if (idx < NN) s += deg[idx]; }
  sh[threadIdx.x] = s; __syncthreads();
  for (int d = 128; d; d >>= 1) { if (threadIdx.x < d) sh[threadIdx.x] += sh[threadIdx.x + d]; __syncthreads(); }
  if (threadIdx.x == 0) bsum[blockIdx.x] = sh[0];
}
__global__ void k_scan2(int* __restrict__ bsum, int nb) {
  if (threadIdx.x == 0 && blockIdx.x == 0) {
    int run = 0;
    for (int i = 0; i < nb; ++i) { int t = bsum[i]; bsum[i] = run; run += t; }
  }
}
__global__ __launch_bounds__(256) void k_scan3(const int* __restrict__ deg, const int* __restrict__ bsum,
                                               int* __restrict__ rowp, int* __restrict__ curs) {
  __shared__ int sh[256];
  int t = threadIdx.x;
  int base = blockIdx.x * 2048 + t * 8;
  int vals[8]; int tot = 0;
#pragma unroll
  for (int j = 0; j < 8; ++j) { int idx = base + j; vals[j] = (idx < NN) ? deg[idx] : 0; tot += vals[j]; }
  sh[t] = tot; __syncthreads();
  for (int d = 1; d < 256; d <<= 1) {
    int v = (t >= d) ? sh[t - d] : 0; __syncthreads();
    sh[t] += v; __syncthreads();
  }
  int run = bsum[blockIdx.x] + sh[t] - tot;
#pragma unroll
  for (int j = 0; j < 8; ++j) {
    int idx = base + j;
    if (idx < NN) {
      rowp[idx] = run; curs[idx] = run; run += vals[j];
      if (idx == NN - 1) rowp[NN] = run;
    }
  }
}
__global__ void k_fill(const int* __restrict__ src, const int* __restrict__ dst,
                       int* __restrict__ curs, int* __restrict__ cols) {
  int i = blockIdx.x * 256 + threadIdx.x;
  if (i < EE) { int pp = atomicAdd(&curs[dst[i]], 1); cols[pp] = src[i]; }
}

// ---------------- gathers (wave per node, CSR) ----------------
__global__ __launch_bounds__(256) void k_gather1(
    const float* __restrict__ x, const float* __restrict__ mask,
    const int* __restrict__ rowp, const int* __restrict__ cols,
    f16* __restrict__ AGG)
{
  int gw = (blockIdx.x * 256 + threadIdx.x) >> 6;
  int lane = threadIdx.x & 63;
  if (gw >= NN) return;
  int beg = rowp[gw], end = rowp[gw + 1];
  float ax0 = 0, ax1 = 0, ax2 = 0, ax3 = 0, ay0 = 0, ay1 = 0, ay2 = 0, ay3 = 0;
  bool act = lane < 21;
  for (int e = beg; e < end; ++e) {
    int s = cols[e];
    if (act) {
      float4 xv = ((const float4*)(x + (size_t)s * 84))[lane];
      float m = mask[s];
      ax0 += xv.x; ax1 += xv.y; ax2 += xv.z; ax3 += xv.w;
      ay0 += xv.x * m; ay1 += xv.y * m; ay2 += xv.z * m; ay3 += xv.w * m;
    }
  }
  if (act) {
    f16x4 hx = {(f16)ax0, (f16)ax1, (f16)ax2, (f16)ax3};
    f16x4 hy = {(f16)ay0, (f16)ay1, (f16)ay2, (f16)ay3};
    ((f16x4*)(AGG + (size_t)gw * 168))[lane] = hx;
    ((f16x4*)(AGG + (size_t)gw * 168 + 84))[lane] = hy;
  }
}
// SUM[gw] = H1[gw] + sum_{nbr} H1[nbr]  (both views interleaved, f16)
__global__ __launch_bounds__(256) void k_gather2(
    const f16* __restrict__ H1, const int* __restrict__ rowp, const int* __restrict__ cols,
    f16* __restrict__ SUM)
{
  int gw = (blockIdx.x * 256 + threadIdx.x) >> 6;
  int lane = threadIdx.x & 63;
  if (gw >= NN) return;
  int beg = rowp[gw], end = rowp[gw + 1];
  float acc[8] = {0, 0, 0, 0, 0, 0, 0, 0};
  bool act = lane < 21;
  if (act) {
    f16x8 own = ((const f16x8*)(H1 + (size_t)gw * 168))[lane];
#pragma unroll
    for (int j = 0; j < 8; ++j) acc[j] = (float)own[j];
  }
  for (int e = beg; e < end; ++e) {
    int s = cols[e];
    if (act) {
      f16x8 vv = ((const f16x8*)(H1 + (size_t)s * 168))[lane];
#pragma unroll
      for (int j = 0; j < 8; ++j) acc[j] += (float)vv[j];
    }
  }
  if (act) {
    f16x8 h;
#pragma unroll
    for (int j = 0; j < 8; ++j) h[j] = (f16)acc[j];
    ((f16x8*)(SUM + (size_t)gw * 168))[lane] = h;
  }
}

// ---------------- GRU (block per (dir, batch-row); Wh in regs) ----------------
__global__ __launch_bounds__(320) void k_gru(
    const float* __restrict__ GIf, const float* __restrict__ GIb,
    const float* __restrict__ whf, const float* __restrict__ whb,
    const float* __restrict__ bhf, const float* __restrict__ bhb,
    float* __restrict__ S)
{
  __shared__ __align__(16) float hL[100];
  __shared__ float ghL[300];
  const int blk = blockIdx.x;
  const int dir = blk / 100, b = blk % 100;
  const float* GI = dir ? GIb : GIf;
  const float* wh = dir ? whb : whf;
  const float* bh = dir ? bhb : bhf;
  const int t = threadIdx.x;
  float4 wr[25];
  float bhr = 0.f;
  if (t < 300) {
#pragma unroll
    for (int kb = 0; kb < 25; ++kb) wr[kb] = ((const float4*)(wh + (size_t)t * 100))[kb];
    bhr = bh[t];
  }
  if (t < 100) hL[t] = 0.f;
  __syncthreads();
  for (int step = 0; step < 100; ++step) {
    int tt = dir ? (99 - step) : step;
    if (t < 300) {
      float p0 = 0.f, p1 = 0.f, p2 = 0.f, p3 = 0.f;
#pragma unroll
      for (int kb = 0; kb < 25; ++kb) {
        float4 h4 = *(const float4*)&hL[kb * 4];
        p0 += wr[kb].x * h4.x; p1 += wr[kb].y * h4.y;
        p2 += wr[kb].z * h4.z; p3 += wr[kb].w * h4.w;
      }
      ghL[t] = bhr + (p0 + p1) + (p2 + p3);
    }
    __syncthreads();
    if (t < 100) {
      const float* gi = GI + ((size_t)tt * 100 + b) * 300;
      float r = 1.f / (1.f + __expf(-(gi[t] + ghL[t])));
      float z = 1.f / (1.f + __expf(-(gi[100 + t] + ghL[100 + t])));
      float n = tanhf(gi[200 + t] + r * ghL[200 + t]);
      float h = (1.f - z) * n + z * hL[t];
      hL[t] = h;
      S[((size_t)tt * 100 + b) * 200 + dir * 100 + t] = fmaxf(h, 0.f);
    }
    __syncthreads();
  }
}

// ---------------- attention softmax (over batch axis) + wsum ----------------
__global__ __launch_bounds__(256) void k_soft(const float* __restrict__ ATT2, float* __restrict__ wsum) {
  __shared__ float mL[256], dL[256];
  const int t = blockIdx.x, c = threadIdx.x;
  const float* A = ATT2 + (size_t)t * 100 * 256;
  float m = -1e30f;
  for (int b = 0; b < 100; ++b) m = fmaxf(m, A[b * 256 + c]);
  float den = 0.f;
  for (int b = 0; b < 100; ++b) den += __expf(A[b * 256 + c] - m);
  mL[c] = m; dL[c] = 1.f / den;
  __syncthreads();
  if (c < 100) {
    float acc = 0.f;
    const float* Ar = A + c * 256;
    for (int k = 0; k < 256; ++k) acc += __expf(Ar[k] - mL[k]) * dL[k];
    wsum[t * 100 + c] = acc;
  }
}
__global__ __launch_bounds__(256) void k_smi(const float* __restrict__ S, const float* __restrict__ wsum,
                                             float* __restrict__ SMI0) {
  const int t = blockIdx.x, c = threadIdx.x;
  if (c < 200) {
    float acc = 0.f;
    for (int b = 0; b < 100; ++b) acc += wsum[t * 100 + b] * S[((size_t)t * 100 + b) * 200 + c];
    SMI0[t * 200 + c] = acc * 0.1f;
  }
}

// ---------------- pool partial reduce (graph size fixed at 1500 nodes) ----------------
__global__ void k_poolred(const float* __restrict__ PP, float* __restrict__ POOL) {
  int i = blockIdx.x * 256 + threadIdx.x;
  if (i >= 2 * 100 * 848) return;
  int v = i / (100 * 848); int r = i % (100 * 848); int g = r / 848; int col = r % 848;
  if (col >= 840) return;
  size_t b0 = (size_t)((v * 100 + g) * 4) * 1696;
  float m = 0.f, s = 0.f;
#pragma unroll
  for (int p = 0; p < 4; ++p) {
    m = fmaxf(m, PP[b0 + (size_t)p * 1696 + col]);
    s += PP[b0 + (size_t)p * 1696 + 848 + col];
  }
  POOL[(size_t)(v * 100 + g) * 1696 + col] = m;
  POOL[(size_t)(v * 100 + g) * 1696 + 840 + col] = s * (1.0f / 1500.0f);
}

// ---------------- misc ----------------
__global__ void k_concat(const float* __restrict__ out, const float* __restrict__ SMI, float* __restrict__ FFIN) {
  int i = blockIdx.x * 256 + threadIdx.x;
  if (i < 100 * 768) {
    int g = i / 768, c = i % 768;
    FFIN[i] = (c < 512) ? out[100 + g * 512 + c] : SMI[g * 256 + (c - 512)];
  }
}
__global__ __launch_bounds__(256) void k_z(const float* __restrict__ FFH, const float* __restrict__ w2,
                                           const float* __restrict__ b2, float* __restrict__ out) {
  __shared__ float part[4];
  const int g = blockIdx.x, t = threadIdx.x;
  float v = FFH[g * 256 + t] * w2[t];
  for (int o = 32; o; o >>= 1) v += __shfl_down(v, o);
  if ((t & 63) == 0) part[t >> 6] = v;
  __syncthreads();
  if (t == 0) out[g] = part[0] + part[1] + part[2] + part[3] + b2[0];
}

// ---------------- weight -> f16 fragment layout prep ----------------
struct PrepArgs {
  const float* src[11];
  f16x8* dst[11];
  int Nw[11], Kw[11], KS[11];
  int slot0[12];
};
__global__ __launch_bounds__(256) void k_prep(PrepArgs pa) {
  int s = blockIdx.x * 256 + threadIdx.x;
  if (s >= pa.slot0[11]) return;
  int wi = 0;
  while (s >= pa.slot0[wi + 1]) ++wi;
  int loc = s - pa.slot0[wi];
  int KS = pa.KS[wi];
  int nt = loc / (KS * 64);
  int rem = loc - nt * KS * 64;
  int ks = rem >> 6, lane = rem & 63;
  int col = (nt << 4) + (lane & 15);
  int kb = ks * 32 + ((lane >> 4) << 3);
  const float* src = pa.src[wi];
  int Nw = pa.Nw[wi], Kw = pa.Kw[wi];
  f16x8 hv;
#pragma unroll
  for (int j = 0; j < 8; ++j) {
    int k = kb + j;
    float v = (col < Nw && k < Kw) ? src[(size_t)col * Kw + k] : 0.f;
    hv[j] = (f16)v;
  }
  pa.dst[wi][loc] = hv;
}

// ==================================================================
extern "C" void kernel_launch(void* const* d_in, const int* in_sizes, int n_in,
                              void* d_out, int out_size, void* d_ws, size_t ws_size,
                              hipStream_t stream) {
  (void)in_sizes; (void)n_in; (void)out_size;
  const float* x      = (const float*)d_in[0];
  const float* smi_em = (const float*)d_in[1];
  const float* mask   = (const float*)d_in[2];
  const int*   eidx   = (const int*)d_in[3];
  const float* wi_f   = (const float*)d_in[5];
  const float* wh_f   = (const float*)d_in[6];
  const float* bi_f   = (const float*)d_in[7];
  const float* bh_f   = (const float*)d_in[8];
  const float* wi_b   = (const float*)d_in[9];
  const float* wh_b   = (const float*)d_in[10];
  const float* bi_b   = (const float*)d_in[11];
  const float* bh_b   = (const float*)d_in[12];
  const float* fc_w1  = (const float*)d_in[13];
  const float* fc_b1  = (const float*)d_in[14];
  const float* fc_w2  = (const float*)d_in[15];
  const float* fc_b2  = (const float*)d_in[16];
  const float* lin_w1 = (const float*)d_in[17];
  const float* lin_b1 = (const float*)d_in[18];
  const float* lin_w2 = (const float*)d_in[19];
  const float* lin_b2 = (const float*)d_in[20];
  const float* conv1_w= (const float*)d_in[21];
  const float* conv1_b= (const float*)d_in[22];
  const float* conv2_w= (const float*)d_in[23];
  const float* conv2_b= (const float*)d_in[24];
  const float* fcg_w1 = (const float*)d_in[25];
  const float* fcg_b1 = (const float*)d_in[26];
  const float* fcg_w2 = (const float*)d_in[27];
  const float* fcg_b2 = (const float*)d_in[28];
  const float* ff_w1  = (const float*)d_in[29];
  const float* ff_b1  = (const float*)d_in[30];
  const float* ff_w2  = (const float*)d_in[31];
  const float* ff_b2  = (const float*)d_in[32];
  float* out = (float*)d_out;

  char* wsb = (char*)d_ws;
  size_t off = 0;
  auto alloc = [&](size_t bytes) -> void* {
    void* p = wsb + off;
    off += (bytes + 255) & ~(size_t)255;
    return p;
  };

  // weight frag buffers
  struct WDesc { const float* src; int Nw, Kw; };
  const WDesc WL[11] = {
    {wi_f, 300, 100}, {wi_b, 300, 100}, {fc_w1, 512, 200}, {fc_w2, 256, 512},
    {lin_w1, 512, 200}, {lin_w2, 256, 512}, {conv1_w, 84, 84}, {conv2_w, 840, 84},
    {fcg_w1, 1024, 1680}, {fcg_w2, 512, 1024}, {ff_w1, 256, 768}};
  PrepArgs pa;
  f16* Wb[11];
  int s0 = 0;
  for (int i = 0; i < 11; ++i) {
    int NT = (WL[i].Nw + 15) / 16, KS = (WL[i].Kw + 31) / 32;
    int slots = NT * KS * 64;
    Wb[i] = (f16*)alloc((size_t)slots * 16);
    pa.src[i] = WL[i].src; pa.dst[i] = (f16x8*)Wb[i];
    pa.Nw[i] = WL[i].Nw; pa.Kw[i] = WL[i].Kw; pa.KS[i] = KS;
    pa.slot0[i] = s0; s0 += slots;
  }
  pa.slot0[11] = s0;

  float* WSUM = (float*)alloc(10000 * 4);
  float* SMI0 = (float*)alloc(100 * 200 * 4);
  float* SMIH = (float*)alloc(100 * 512 * 4);
  float* SMI  = (float*)alloc(100 * 256 * 4);
  int* DEG  = (int*)alloc((size_t)NN * 4);
  int* ROWP = (int*)alloc((size_t)(NN + 1) * 4);
  int* CURS = (int*)alloc((size_t)NN * 4);
  int* COLS = (int*)alloc((size_t)EE * 4);
  int* BSUM = (int*)alloc(1024);
  float* PP   = (float*)alloc((size_t)800 * 1696 * 4);
  float* POOL = (float*)alloc((size_t)200 * 1696 * 4);
  float* FCGH = (float*)alloc((size_t)200 * 1024 * 4);
  float* FFIN = (float*)alloc(100 * 768 * 4);
  float* FFH  = (float*)alloc(100 * 256 * 4);
  // big overlapped region: SMILES buffers (phase 1) / graph buffers (phase 2)
  char* R = (char*)alloc(100800000);
  f16* AGG = (f16*)R;                    // gin1 aggregate, later reused as SUM
  f16* H1  = (f16*)(R + 50400000);
  f16* SUM = AGG;                        // gather2 output (AGG is dead by then)
  float* GIf  = (float*)R;
  float* GIb  = (float*)(R + 12000000);
  float* S    = (float*)(R + 24000000);
  float* ATT1 = (float*)(R + 32000000);
  float* ATT2 = (float*)(R + 52480000);
  if (ws_size < off) return;  // workspace too small: bail (will fail validation loudly)

  const int* esrc = eidx;
  const int* edst = eidx + EE;
  const float* FNULL = nullptr;

  // ---- weight prep ----
  k_prep<<<(s0 + 255) / 256, 256, 0, stream>>>(pa);

  // ---- SMILES branch ----
  k_gemm<float, float, float, 0><<<dim3(157, 3), 256, 0, stream>>>(smi_em, 100, nullptr, FNULL, 0, Wb[0], bi_f, GIf, 300, 10000, 100, 300, 4, 19);
  k_gemm<float, float, float, 0><<<dim3(157, 3), 256, 0, stream>>>(smi_em, 100, nullptr, FNULL, 0, Wb[1], bi_b, GIb, 300, 10000, 100, 300, 4, 19);
  k_gru<<<200, 320, 0, stream>>>(GIf, GIb, wh_f, wh_b, bh_f, bh_b, S);
  k_gemm<float, float, float, 1><<<dim3(157, 4), 256, 0, stream>>>(S, 200, nullptr, FNULL, 0, Wb[2], fc_b1, ATT1, 512, 10000, 200, 512, 7, 32);
  k_gemm<float, float, float, 2><<<dim3(157, 2), 256, 0, stream>>>(ATT1, 512, nullptr, FNULL, 0, Wb[3], fc_b2, ATT2, 256, 10000, 512, 256, 16, 16);
  k_soft<<<100, 256, 0, stream>>>(ATT2, WSUM);
  k_smi<<<100, 256, 0, stream>>>(S, WSUM, SMI0);
  k_gemm<float, float, float, 0><<<dim3(2, 4), 256, 0, stream>>>(SMI0, 200, nullptr, FNULL, 0, Wb[4], lin_b1, SMIH, 512, 100, 200, 512, 7, 32);
  k_gemm<float, float, float, 0><<<dim3(2, 2), 256, 0, stream>>>(SMIH, 512, nullptr, FNULL, 0, Wb[5], lin_b2, SMI, 256, 100, 512, 256, 16, 16);

  // ---- graph branch: CSR ----
  hipMemsetAsync(DEG, 0, (size_t)NN * 4, stream);
  k_hist<<<(EE + 255) / 256, 256, 0, stream>>>(edst, DEG);
  k_scan1<<<74, 256, 0, stream>>>(DEG, BSUM);
  k_scan2<<<1, 64, 0, stream>>>(BSUM, 74);
  k_scan3<<<74, 256, 0, stream>>>(DEG, BSUM, ROWP, CURS);
  k_fill<<<(EE + 255) / 256, 256, 0, stream>>>(esrc, edst, CURS, COLS);

  // ---- gin1 ----
  k_gather1<<<NN / 4, 256, 0, stream>>>(x, mask, ROWP, COLS, AGG);
  k_gemm<float, f16, f16, 1><<<dim3(2344, 1), 256, 0, stream>>>(x, 84, nullptr, (const f16*)AGG, 168, Wb[6], conv1_b, H1, 168, NN, 84, 84, 3, 6);
  k_gemm<float, f16, f16, 1><<<dim3(2344, 1), 256, 0, stream>>>(x, 84, mask, (const f16*)(AGG + 84), 168, Wb[6], conv1_b, H1 + 84, 168, NN, 84, 84, 3, 6);

  // ---- gin2 + pooling ----
  k_gather2<<<NN / 4, 256, 0, stream>>>(H1, ROWP, COLS, SUM);
  k_gin2pool<<<dim3(800, 4), 256, 0, stream>>>(SUM, Wb[7], conv2_b, PP);
  k_poolred<<<(2 * 100 * 848 + 255) / 256, 256, 0, stream>>>(PP, POOL);

  // ---- fcg MLP (both views at once: M=200; writes x_g then y_g into d_out) ----
  k_gemm<float, float, float, 1><<<dim3(4, 8), 256, 0, stream>>>(POOL, 1696, nullptr, FNULL, 0, Wb[8], fcg_b1, FCGH, 1024, 200, 1680, 1024, 53, 64);
  k_gemm<float, float, float, 0><<<dim3(4, 4), 256, 0, stream>>>(FCGH, 1024, nullptr, FNULL, 0, Wb[9], fcg_b2, out + 100, 512, 200, 1024, 512, 32, 32);

  // ---- final head ----
  k_concat<<<300, 256, 0, stream>>>(out, SMI, FFIN);
  k_gemm<float, float, float, 1><<<dim3(2, 2), 256, 0, stream>>>(FFIN, 768, nullptr, FNULL, 0, Wb[10], ff_b1, FFH, 256, 100, 768, 256, 24, 16);
  k_z<<<100, 256, 0, stream>>>(FFH, ff_w2, ff_b2, out);
}

// Round 10
// 1372.520 us; speedup vs baseline: 1.6964x; 1.2685x over previous
//
#include <hip/hip_runtime.h>

typedef _Float16 f16;
typedef f16  f16x8 __attribute__((ext_vector_type(8)));
typedef f16  f16x4 __attribute__((ext_vector_type(4)));
typedef float f32x4 __attribute__((ext_vector_type(4)));

constexpr int NN = 150000;
constexpr int EE = 1200000;

// ------------------------------------------------------------------
// Generic MFMA f16 GEMM:  C = act( A @ W^T + bias ), A fp32.
// W pre-laid in fragment-linear layout: frag[(ntile*KS+ks)*64+lane][8]
// A rows staged to LDS per 32-k chunk (vectorized fast path when the
// 8-elem octet is fully in-bounds). Block=256 thr, 64 M-rows/block.
// blockIdx.y picks an 8-ntile (128-col) N-chunk: one staging pass per block.
// ------------------------------------------------------------------
template<class TC, int ACT>
__global__ __launch_bounds__(256) void k_gemm(
    const float* __restrict__ A, int rsA,
    const f16* __restrict__ W, const float* __restrict__ bias,
    TC* __restrict__ C, int rsC,
    int M, int K, int N, int KS, int NT)
{
  __shared__ f16x8 As8[256];
  const int tid  = threadIdx.x;
  const int lane = tid & 63, wave = tid >> 6;
  const int m0   = blockIdx.x * 64;
  const int sr   = tid >> 2, scb = tid & 3;
  const int grow = m0 + sr;
  const bool rv  = grow < M;
  const f16x8* __restrict__ W8 = (const f16x8*)W;
  const float* __restrict__ ap = A + (size_t)(rv ? grow : 0) * rsA;

  const int nc  = blockIdx.y << 3;
  if (nc >= NT) return;
  const int nth = (NT - nc) < 8 ? (NT - nc) : 8;
  f32x4 acc[8];
#pragma unroll
  for (int i = 0; i < 8; ++i) acc[i] = (f32x4){0.f, 0.f, 0.f, 0.f};
  for (int ks = 0; ks < KS; ++ks) {
    const int k0 = ks * 32 + scb * 8;
    f16x8 hv;
    if (rv && k0 + 8 <= K) {
      float4 v0 = *(const float4*)(ap + k0);
      float4 v1 = *(const float4*)(ap + k0 + 4);
      hv[0] = (f16)v0.x; hv[1] = (f16)v0.y; hv[2] = (f16)v0.z; hv[3] = (f16)v0.w;
      hv[4] = (f16)v1.x; hv[5] = (f16)v1.y; hv[6] = (f16)v1.z; hv[7] = (f16)v1.w;
    } else {
#pragma unroll
      for (int j = 0; j < 8; ++j) {
        int k = k0 + j;
        hv[j] = (f16)((rv && k < K) ? ap[k] : 0.f);
      }
    }
    As8[((sr >> 4) << 6) | (sr & 15) | (scb << 4)] = hv;
    __syncthreads();
    const f16x8 a = As8[(wave << 6) | lane];
#pragma unroll
    for (int nt = 0; nt < 8; ++nt) {
      if (nt < nth) {
        f16x8 b = W8[((size_t)(nc + nt) * KS + ks) * 64 + lane];
        acc[nt] = __builtin_amdgcn_mfma_f32_16x16x32_f16(a, b, acc[nt], 0, 0, 0);
      }
    }
    __syncthreads();
  }
  const int colb  = (nc << 4) + (lane & 15);
  const int rbase = m0 + (wave << 4) + ((lane >> 4) << 2);
#pragma unroll
  for (int nt = 0; nt < 8; ++nt) {
    if (nt < nth) {
      int col = colb + (nt << 4);
      if (col < N) {
        float bb = bias ? bias[col] : 0.f;
#pragma unroll
        for (int j = 0; j < 4; ++j) {
          int r = rbase + j;
          if (r < M) {
            float v = acc[nt][j] + bb;
            if (ACT == 1) v = fmaxf(v, 0.f);
            else if (ACT == 2) v = tanhf(v);
            C[(size_t)r * rsC + col] = (TC)v;
          }
        }
      }
    }
  }
}

// ------------------------------------------------------------------
// Fused gin1: H1[r] = relu((x[r]+agg0[r]) @ W^T + b)  (view0, cols 0..83)
//             H1[r+84.] = relu((x[r]*mask[r]+agg1[r]) @ W^T + b)  (view1)
// Direct-from-global A fragments (no LDS, no barriers); one W-fragment
// load feeds both views. Block = 64 rows, 6 ntiles, KS=3.
// ------------------------------------------------------------------
__global__ __launch_bounds__(256) void k_gin1(
    const float* __restrict__ x, const float* __restrict__ mask,
    const f16* __restrict__ AGG,
    const f16* __restrict__ W, const float* __restrict__ bias,
    f16* __restrict__ H1)
{
  const int tid = threadIdx.x, lane = tid & 63, wave = tid >> 6;
  const int m0 = blockIdx.x * 64;
  const int arow = (wave << 4) | (lane & 15);
  const int row = m0 + arow;
  const bool ok = row < NN;
  const int kgrp = (lane >> 4) << 3;          // 0,8,16,24
  const f16x8* __restrict__ W8 = (const f16x8*)W;

  const float mk = ok ? mask[row] : 0.f;
  const float* __restrict__ xp = x + (size_t)(ok ? row : 0) * 84;
  const f16*   __restrict__ gp = AGG + (size_t)(ok ? row : 0) * 168;

  f16x8 a0[3], a1[3];
#pragma unroll
  for (int ks = 0; ks < 3; ++ks) {
    const int kb = ks * 32 + kgrp;            // 0..88, multiple of 8
    float xv[8];
    if (kb + 8 <= 84) {
      float4 v0 = *(const float4*)(xp + kb);
      float4 v1 = *(const float4*)(xp + kb + 4);
      xv[0]=v0.x; xv[1]=v0.y; xv[2]=v0.z; xv[3]=v0.w;
      xv[4]=v1.x; xv[5]=v1.y; xv[6]=v1.z; xv[7]=v1.w;
    } else if (kb < 84) {
      float4 v0 = *(const float4*)(xp + kb);
      xv[0]=v0.x; xv[1]=v0.y; xv[2]=v0.z; xv[3]=v0.w;
      xv[4]=0.f; xv[5]=0.f; xv[6]=0.f; xv[7]=0.f;
    } else {
#pragma unroll
      for (int j = 0; j < 8; ++j) xv[j] = 0.f;
    }
    const f16x4 z4 = {(f16)0, (f16)0, (f16)0, (f16)0};
    f16x4 gl0 = (kb     < 84) ? *(const f16x4*)(gp + kb)          : z4;
    f16x4 gh0 = (kb + 4 < 84) ? *(const f16x4*)(gp + kb + 4)      : z4;
    f16x4 gl1 = (kb     < 84) ? *(const f16x4*)(gp + 84 + kb)     : z4;
    f16x4 gh1 = (kb + 4 < 84) ? *(const f16x4*)(gp + 84 + kb + 4) : z4;
    f16x8 f0, f1;
#pragma unroll
    for (int j = 0; j < 4; ++j) {
      f0[j]     = (f16)(xv[j]          + (float)gl0[j]);
      f0[4 + j] = (f16)(xv[4 + j]      + (float)gh0[j]);
      f1[j]     = (f16)(xv[j] * mk     + (float)gl1[j]);
      f1[4 + j] = (f16)(xv[4 + j] * mk + (float)gh1[j]);
    }
    a0[ks] = f0; a1[ks] = f1;
  }

  f32x4 acc0[6], acc1[6];
#pragma unroll
  for (int nt = 0; nt < 6; ++nt) {
    acc0[nt] = (f32x4){0.f, 0.f, 0.f, 0.f};
    acc1[nt] = (f32x4){0.f, 0.f, 0.f, 0.f};
  }
#pragma unroll
  for (int nt = 0; nt < 6; ++nt) {
#pragma unroll
    for (int ks = 0; ks < 3; ++ks) {
      f16x8 b = W8[(nt * 3 + ks) * 64 + lane];
      acc0[nt] = __builtin_amdgcn_mfma_f32_16x16x32_f16(a0[ks], b, acc0[nt], 0, 0, 0);
      acc1[nt] = __builtin_amdgcn_mfma_f32_16x16x32_f16(a1[ks], b, acc1[nt], 0, 0, 0);
    }
  }

  const int colb  = lane & 15;
  const int rbase = m0 + (wave << 4) + ((lane >> 4) << 2);
#pragma unroll
  for (int nt = 0; nt < 6; ++nt) {
    int col = (nt << 4) + colb;
    if (col < 84) {
      float bb = bias[col];
#pragma unroll
      for (int j = 0; j < 4; ++j) {
        int r = rbase + j;
        if (r < NN) {
          H1[(size_t)r * 168 + col]      = (f16)fmaxf(acc0[nt][j] + bb, 0.f);
          H1[(size_t)r * 168 + 84 + col] = (f16)fmaxf(acc1[nt][j] + bb, 0.f);
        }
      }
    }
  }
}

// ------------------------------------------------------------------
// gin2 + fused max/mean pooling, LDS-free A path, 4 column chunks.
// Input SUM = H1 + agg (f16, (N,168), both views) precomputed by k_gather2.
// ------------------------------------------------------------------
__global__ __launch_bounds__(256) void k_gin2pool(
    const f16* __restrict__ SUM,
    const f16* __restrict__ W, const float* __restrict__ bias,
    float* __restrict__ PP)
{
  __shared__ float Red[4][14][2][16];
  const int blk = blockIdx.x;
  const int cc  = blockIdx.y;                 // column chunk 0..3
  const int ntBase = cc * 14;
  const int ntc = (cc < 3) ? 14 : 11;
  const int v = blk / 400;
  const int g = (blk / 4) % 100;
  const int p = blk & 3;
  const int nodeBeg = g * 1500 + p * 375;
  const int tid = threadIdx.x, lane = tid & 63, wave = tid >> 6;
  const int voff = v * 84;
  const f16x8* __restrict__ W8 = (const f16x8*)W;
  const int rloc = (wave << 4) + ((lane >> 4) << 2);
  const int arow = (wave << 4) + (lane & 15);
  const int kgrp = (lane >> 4) << 3;          // 0,8,16,24
  float mx[14], sm[14];
#pragma unroll
  for (int i = 0; i < 14; ++i) { mx[i] = 0.f; sm[i] = 0.f; }

  for (int ch = 0; ch < 6; ++ch) {
    const int lr = ch * 64 + arow;
    const f16* rp = SUM + (size_t)(nodeBeg + lr) * 168 + voff;
    f16x8 a[3];
#pragma unroll
    for (int ks = 0; ks < 3; ++ks) {
      const int kb = ks * 32 + kgrp;          // 0..88, multiple of 8
      f16x4 lo = (kb     < 84) ? *(const f16x4*)(rp + kb)     : (f16x4){0,0,0,0};
      f16x4 hi = (kb + 4 < 84) ? *(const f16x4*)(rp + kb + 4) : (f16x4){0,0,0,0};
      f16x8 av;
      av[0]=lo[0]; av[1]=lo[1]; av[2]=lo[2]; av[3]=lo[3];
      av[4]=hi[0]; av[5]=hi[1]; av[6]=hi[2]; av[7]=hi[3];
      a[ks] = av;
    }
    const int rem = 375 - (ch * 64 + rloc);   // #valid rows among this lane's 4
#pragma unroll
    for (int nt = 0; nt < 14; ++nt) {
      if (nt < ntc) {
        const int ntg = ntBase + nt;
        f32x4 acc = (f32x4){0.f, 0.f, 0.f, 0.f};
        acc = __builtin_amdgcn_mfma_f32_16x16x32_f16(a[0], W8[(ntg * 3 + 0) * 64 + lane], acc, 0, 0, 0);
        acc = __builtin_amdgcn_mfma_f32_16x16x32_f16(a[1], W8[(ntg * 3 + 1) * 64 + lane], acc, 0, 0, 0);
        acc = __builtin_amdgcn_mfma_f32_16x16x32_f16(a[2], W8[(ntg * 3 + 2) * 64 + lane], acc, 0, 0, 0);
        const int col = (ntg << 4) + (lane & 15);
        const float bb = (col < 840) ? bias[col] : 0.f;
#pragma unroll
        for (int j = 0; j < 4; ++j) {
          float r = fmaxf(acc[j] + bb, 0.f);   // relu
          if (j >= rem) r = 0.f;               // mask padded rows
          mx[nt] = fmaxf(mx[nt], r);
          sm[nt] += r;
        }
      }
    }
  }
#pragma unroll
  for (int nt = 0; nt < 14; ++nt) {
    if (nt < ntc) {
      float m = mx[nt], s = sm[nt];
      m = fmaxf(m, __shfl_xor(m, 16)); s += __shfl_xor(s, 16);
      m = fmaxf(m, __shfl_xor(m, 32)); s += __shfl_xor(s, 32);
      if (lane < 16) { Red[wave][nt][0][lane] = m; Red[wave][nt][1][lane] = s; }
    }
  }
  __syncthreads();
  const size_t base = (size_t)blk * 1696 + ((size_t)ntBase << 4);
  for (int u = tid; u < ntc * 16; u += 256) {
    int nt = u >> 4, c = u & 15;
    float m = fmaxf(fmaxf(Red[0][nt][0][c], Red[1][nt][0][c]),
                    fmaxf(Red[2][nt][0][c], Red[3][nt][0][c]));
    float s = Red[0][nt][1][c] + Red[1][nt][1][c] + Red[2][nt][1][c] + Red[3][nt][1][c];
    PP[base + u]       = m;
    PP[base + 848 + u] = s;
  }
}

// ---------------- CSR build ----------------
__global__ void k_hist(const int* __restrict__ dst, int* __restrict__ deg) {
  int i = blockIdx.x * 256 + threadIdx.x;
  if (i < EE) atomicAdd(&deg[dst[i]], 1);
}
__global__ __launch_bounds__(256) void k_scan1(const int* __restrict__ deg, int* __restrict__ bsum) {
  __shared__ int sh[256];
  int base = blockIdx.x * 2048 + threadIdx.x * 8;
  int s = 0;
#pragma unroll
  for (int j = 0; j < 8; ++j) { int idx = base + j; if (idx < NN) s += deg[idx]; }
  sh[threadIdx.x] = s; __syncthreads();
  for (int d = 128; d; d >>= 1) { if (threadIdx.x < d) sh[threadIdx.x] += sh[threadIdx.x + d]; __syncthreads(); }
  if (threadIdx.x == 0) bsum[blockIdx.x] = sh[0];
}
__global__ void k_scan2(int* __restrict__ bsum, int nb) {
  if (threadIdx.x == 0 && blockIdx.x == 0) {
    int run = 0;
    for (int i = 0; i < nb; ++i) { int t = bsum[i]; bsum[i] = run; run += t; }
  }
}
__global__ __launch_bounds__(256) void k_scan3(const int* __restrict__ deg, const int* __restrict__ bsum,
                                               int* __restrict__ rowp, int* __restrict__ curs) {
  __shared__ int sh[256];
  int t = threadIdx.x;
  int base = blockIdx.x * 2048 + t * 8;
  int vals[8]; int tot = 0;
#pragma unroll
  for (int j = 0; j < 8; ++j) { int idx = base + j; vals[j] = (idx < NN) ? deg[idx] : 0; tot += vals[j]; }
  sh[t] = tot; __syncthreads();
  for (int d = 1; d < 256; d <<= 1) {
    int v = (t >= d) ? sh[t - d] : 0; __syncthreads();
    sh[t] += v; __syncthreads();
  }
  int run = bsum[blockIdx.x] + sh[t] - tot;
#pragma unroll
  for (int j = 0; j < 8; ++j) {
    int idx = base + j;
    if (idx < NN) {
      rowp[idx] = run; curs[idx] = run; run += vals[j];
      if (idx == NN - 1) rowp[NN] = run;
    }
  }
}
__global__ void k_fill(const int* __restrict__ src, const int* __restrict__ dst,
                       int* __restrict__ curs, int* __restrict__ cols) {
  int i = blockIdx.x * 256 + threadIdx.x;
  if (i < EE) { int pp = atomicAdd(&curs[dst[i]], 1); cols[pp] = src[i]; }
}

// ---------------- gathers (3 nodes per wave, 21 lanes each) ----------------
__global__ __launch_bounds__(256) void k_gather1(
    const float* __restrict__ x, const float* __restrict__ mask,
    const int* __restrict__ rowp, const int* __restrict__ cols,
    f16* __restrict__ AGG)
{
  int wid = (blockIdx.x * 256 + threadIdx.x) >> 6;
  int lane = threadIdx.x & 63;
  int sub = lane / 21, slot = lane - sub * 21;   // sub 0..3 (3 = idle lane 63)
  int gw = wid * 3 + sub;
  bool act = (sub < 3) && (gw < NN);
  int beg = 0, end = 0;
  if (act) { beg = rowp[gw]; end = rowp[gw + 1]; }
  float ax0 = 0, ax1 = 0, ax2 = 0, ax3 = 0, ay0 = 0, ay1 = 0, ay2 = 0, ay3 = 0;
  for (int e = beg; e < end; ++e) {
    int s = cols[e];
    float4 xv = ((const float4*)(x + (size_t)s * 84))[slot];
    float m = mask[s];
    ax0 += xv.x; ax1 += xv.y; ax2 += xv.z; ax3 += xv.w;
    ay0 += xv.x * m; ay1 += xv.y * m; ay2 += xv.z * m; ay3 += xv.w * m;
  }
  if (act) {
    f16x4 hx = {(f16)ax0, (f16)ax1, (f16)ax2, (f16)ax3};
    f16x4 hy = {(f16)ay0, (f16)ay1, (f16)ay2, (f16)ay3};
    ((f16x4*)(AGG + (size_t)gw * 168))[slot] = hx;
    ((f16x4*)(AGG + (size_t)gw * 168 + 84))[slot] = hy;
  }
}
// SUM[gw] = H1[gw] + sum_{nbr} H1[nbr]  (both views interleaved, f16)
__global__ __launch_bounds__(256) void k_gather2(
    const f16* __restrict__ H1, const int* __restrict__ rowp, const int* __restrict__ cols,
    f16* __restrict__ SUM)
{
  int wid = (blockIdx.x * 256 + threadIdx.x) >> 6;
  int lane = threadIdx.x & 63;
  int sub = lane / 21, slot = lane - sub * 21;
  int gw = wid * 3 + sub;
  bool act = (sub < 3) && (gw < NN);
  int beg = 0, end = 0;
  float acc[8] = {0, 0, 0, 0, 0, 0, 0, 0};
  if (act) {
    beg = rowp[gw]; end = rowp[gw + 1];
    f16x8 own = ((const f16x8*)(H1 + (size_t)gw * 168))[slot];
#pragma unroll
    for (int j = 0; j < 8; ++j) acc[j] = (float)own[j];
  }
  for (int e = beg; e < end; ++e) {
    int s = cols[e];
    f16x8 vv = ((const f16x8*)(H1 + (size_t)s * 168))[slot];
#pragma unroll
    for (int j = 0; j < 8; ++j) acc[j] += (float)vv[j];
  }
  if (act) {
    f16x8 h;
#pragma unroll
    for (int j = 0; j < 8; ++j) h[j] = (f16)acc[j];
    ((f16x8*)(SUM + (size_t)gw * 168))[slot] = h;
  }
}

// ---------------- GRU (block per (dir, batch-row); Wh in regs) ----------------
__global__ __launch_bounds__(320) void k_gru(
    const float* __restrict__ GIf, const float* __restrict__ GIb,
    const float* __restrict__ whf, const float* __restrict__ whb,
    const float* __restrict__ bhf, const float* __restrict__ bhb,
    float* __restrict__ S)
{
  __shared__ __align__(16) float hL[100];
  __shared__ float ghL[300];
  const int blk = blockIdx.x;
  const int dir = blk / 100, b = blk % 100;
  const float* GI = dir ? GIb : GIf;
  const float* wh = dir ? whb : whf;
  const float* bh = dir ? bhb : bhf;
  const int t = threadIdx.x;
  float4 wr[25];
  float bhr = 0.f;
  if (t < 300) {
#pragma unroll
    for (int kb = 0; kb < 25; ++kb) wr[kb] = ((const float4*)(wh + (size_t)t * 100))[kb];
    bhr = bh[t];
  }
  if (t < 100) hL[t] = 0.f;
  __syncthreads();
  for (int step = 0; step < 100; ++step) {
    int tt = dir ? (99 - step) : step;
    if (t < 300) {
      float p0 = 0.f, p1 = 0.f, p2 = 0.f, p3 = 0.f;
#pragma unroll
      for (int kb = 0; kb < 25; ++kb) {
        float4 h4 = *(const float4*)&hL[kb * 4];
        p0 += wr[kb].x * h4.x; p1 += wr[kb].y * h4.y;
        p2 += wr[kb].z * h4.z; p3 += wr[kb].w * h4.w;
      }
      ghL[t] = bhr + (p0 + p1) + (p2 + p3);
    }
    __syncthreads();
    if (t < 100) {
      const float* gi = GI + ((size_t)tt * 100 + b) * 300;
      float r = 1.f / (1.f + __expf(-(gi[t] + ghL[t])));
      float z = 1.f / (1.f + __expf(-(gi[100 + t] + ghL[100 + t])));
      float n = tanhf(gi[200 + t] + r * ghL[200 + t]);
      float h = (1.f - z) * n + z * hL[t];
      hL[t] = h;
      S[((size_t)tt * 100 + b) * 200 + dir * 100 + t] = fmaxf(h, 0.f);
    }
    __syncthreads();
  }
}

// ---------------- attention softmax (over batch axis) + wsum ----------------
__global__ __launch_bounds__(256) void k_soft(const float* __restrict__ ATT2, float* __restrict__ wsum) {
  __shared__ float mL[256], dL[256];
  const int t = blockIdx.x, c = threadIdx.x;
  const float* A = ATT2 + (size_t)t * 100 * 256;
  float m = -1e30f;
  for (int b = 0; b < 100; ++b) m = fmaxf(m, A[b * 256 + c]);
  float den = 0.f;
  for (int b = 0; b < 100; ++b) den += __expf(A[b * 256 + c] - m);
  mL[c] = m; dL[c] = 1.f / den;
  __syncthreads();
  if (c < 100) {
    float acc = 0.f;
    const float* Ar = A + c * 256;
    for (int k = 0; k < 256; ++k) acc += __expf(Ar[k] - mL[k]) * dL[k];
    wsum[t * 100 + c] = acc;
  }
}
__global__ __launch_bounds__(256) void k_smi(const float* __restrict__ S, const float* __restrict__ wsum,
                                             float* __restrict__ SMI0) {
  const int t = blockIdx.x, c = threadIdx.x;
  if (c < 200) {
    float acc = 0.f;
    for (int b = 0; b < 100; ++b) acc += wsum[t * 100 + b] * S[((size_t)t * 100 + b) * 200 + c];
    SMI0[t * 200 + c] = acc * 0.1f;
  }
}

// ---------------- pool partial reduce (graph size fixed at 1500 nodes) ----------------
__global__ void k_poolred(const float* __restrict__ PP, float* __restrict__ POOL) {
  int i = blockIdx.x * 256 + threadIdx.x;
  if (i >= 2 * 100 * 848) return;
  int v = i / (100 * 848); int r = i % (100 * 848); int g = r / 848; int col = r % 848;
  if (col >= 840) return;
  size_t b0 = (size_t)((v * 100 + g) * 4) * 1696;
  float m = 0.f, s = 0.f;
#pragma unroll
  for (int p = 0; p < 4; ++p) {
    m = fmaxf(m, PP[b0 + (size_t)p * 1696 + col]);
    s += PP[b0 + (size_t)p * 1696 + 848 + col];
  }
  POOL[(size_t)(v * 100 + g) * 1696 + col] = m;
  POOL[(size_t)(v * 100 + g) * 1696 + 840 + col] = s * (1.0f / 1500.0f);
}

// ---------------- misc ----------------
__global__ void k_concat(const float* __restrict__ out, const float* __restrict__ SMI, float* __restrict__ FFIN) {
  int i = blockIdx.x * 256 + threadIdx.x;
  if (i < 100 * 768) {
    int g = i / 768, c = i % 768;
    FFIN[i] = (c < 512) ? out[100 + g * 512 + c] : SMI[g * 256 + (c - 512)];
  }
}
__global__ __launch_bounds__(256) void k_z(const float* __restrict__ FFH, const float* __restrict__ w2,
                                           const float* __restrict__ b2, float* __restrict__ out) {
  __shared__ float part[4];
  const int g = blockIdx.x, t = threadIdx.x;
  float v = FFH[g * 256 + t] * w2[t];
  for (int o = 32; o; o >>= 1) v += __shfl_down(v, o);
  if ((t & 63) == 0) part[t >> 6] = v;
  __syncthreads();
  if (t == 0) out[g] = part[0] + part[1] + part[2] + part[3] + b2[0];
}

// ---------------- weight -> f16 fragment layout prep ----------------
struct PrepArgs {
  const float* src[11];
  f16x8* dst[11];
  int Nw[11], Kw[11], KS[11];
  int slot0[12];
};
__global__ __launch_bounds__(256) void k_prep(PrepArgs pa) {
  int s = blockIdx.x * 256 + threadIdx.x;
  if (s >= pa.slot0[11]) return;
  int wi = 0;
  while (s >= pa.slot0[wi + 1]) ++wi;
  int loc = s - pa.slot0[wi];
  int KS = pa.KS[wi];
  int nt = loc / (KS * 64);
  int rem = loc - nt * KS * 64;
  int ks = rem >> 6, lane = rem & 63;
  int col = (nt << 4) + (lane & 15);
  int kb = ks * 32 + ((lane >> 4) << 3);
  const float* src = pa.src[wi];
  int Nw = pa.Nw[wi], Kw = pa.Kw[wi];
  f16x8 hv;
#pragma unroll
  for (int j = 0; j < 8; ++j) {
    int k = kb + j;
    float v = (col < Nw && k < Kw) ? src[(size_t)col * Kw + k] : 0.f;
    hv[j] = (f16)v;
  }
  pa.dst[wi][loc] = hv;
}

// ==================================================================
extern "C" void kernel_launch(void* const* d_in, const int* in_sizes, int n_in,
                              void* d_out, int out_size, void* d_ws, size_t ws_size,
                              hipStream_t stream) {
  (void)in_sizes; (void)n_in; (void)out_size;
  const float* x      = (const float*)d_in[0];
  const float* smi_em = (const float*)d_in[1];
  const float* mask   = (const float*)d_in[2];
  const int*   eidx   = (const int*)d_in[3];
  const float* wi_f   = (const float*)d_in[5];
  const float* wh_f   = (const float*)d_in[6];
  const float* bi_f   = (const float*)d_in[7];
  const float* bh_f   = (const float*)d_in[8];
  const float* wi_b   = (const float*)d_in[9];
  const float* wh_b   = (const float*)d_in[10];
  const float* bi_b   = (const float*)d_in[11];
  const float* bh_b   = (const float*)d_in[12];
  const float* fc_w1  = (const float*)d_in[13];
  const float* fc_b1  = (const float*)d_in[14];
  const float* fc_w2  = (const float*)d_in[15];
  const float* fc_b2  = (const float*)d_in[16];
  const float* lin_w1 = (const float*)d_in[17];
  const float* lin_b1 = (const float*)d_in[18];
  const float* lin_w2 = (const float*)d_in[19];
  const float* lin_b2 = (const float*)d_in[20];
  const float* conv1_w= (const float*)d_in[21];
  const float* conv1_b= (const float*)d_in[22];
  const float* conv2_w= (const float*)d_in[23];
  const float* conv2_b= (const float*)d_in[24];
  const float* fcg_w1 = (const float*)d_in[25];
  const float* fcg_b1 = (const float*)d_in[26];
  const float* fcg_w2 = (const float*)d_in[27];
  const float* fcg_b2 = (const float*)d_in[28];
  const float* ff_w1  = (const float*)d_in[29];
  const float* ff_b1  = (const float*)d_in[30];
  const float* ff_w2  = (const float*)d_in[31];
  const float* ff_b2  = (const float*)d_in[32];
  float* out = (float*)d_out;

  char* wsb = (char*)d_ws;
  size_t off = 0;
  auto alloc = [&](size_t bytes) -> void* {
    void* p = wsb + off;
    off += (bytes + 255) & ~(size_t)255;
    return p;
  };

  // weight frag buffers
  struct WDesc { const float* src; int Nw, Kw; };
  const WDesc WL[11] = {
    {wi_f, 300, 100}, {wi_b, 300, 100}, {fc_w1, 512, 200}, {fc_w2, 256, 512},
    {lin_w1, 512, 200}, {lin_w2, 256, 512}, {conv1_w, 84, 84}, {conv2_w, 840, 84},
    {fcg_w1, 1024, 1680}, {fcg_w2, 512, 1024}, {ff_w1, 256, 768}};
  PrepArgs pa;
  f16* Wb[11];
  int s0 = 0;
  for (int i = 0; i < 11; ++i) {
    int NT = (WL[i].Nw + 15) / 16, KS = (WL[i].Kw + 31) / 32;
    int slots = NT * KS * 64;
    Wb[i] = (f16*)alloc((size_t)slots * 16);
    pa.src[i] = WL[i].src; pa.dst[i] = (f16x8*)Wb[i];
    pa.Nw[i] = WL[i].Nw; pa.Kw[i] = WL[i].Kw; pa.KS[i] = KS;
    pa.slot0[i] = s0; s0 += slots;
  }
  pa.slot0[11] = s0;

  float* WSUM = (float*)alloc(10000 * 4);
  float* SMI0 = (float*)alloc(100 * 200 * 4);
  float* SMIH = (float*)alloc(100 * 512 * 4);
  float* SMI  = (float*)alloc(100 * 256 * 4);
  int* DEG  = (int*)alloc((size_t)NN * 4);
  int* ROWP = (int*)alloc((size_t)(NN + 1) * 4);
  int* CURS = (int*)alloc((size_t)NN * 4);
  int* COLS = (int*)alloc((size_t)EE * 4);
  int* BSUM = (int*)alloc(1024);
  float* PP   = (float*)alloc((size_t)800 * 1696 * 4);
  float* POOL = (float*)alloc((size_t)200 * 1696 * 4);
  float* FCGH = (float*)alloc((size_t)200 * 1024 * 4);
  float* FFIN = (float*)alloc(100 * 768 * 4);
  float* FFH  = (float*)alloc(100 * 256 * 4);
  // big overlapped region: SMILES buffers (phase 1) / graph buffers (phase 2)
  char* R = (char*)alloc(100800000);
  f16* AGG = (f16*)R;                    // gin1 aggregate, later reused as SUM
  f16* H1  = (f16*)(R + 50400000);
  f16* SUM = AGG;                        // gather2 output (AGG is dead by then)
  float* GIf  = (float*)R;
  float* GIb  = (float*)(R + 12000000);
  float* S    = (float*)(R + 24000000);
  float* ATT1 = (float*)(R + 32000000);
  float* ATT2 = (float*)(R + 52480000);
  if (ws_size < off) return;  // workspace too small: bail (will fail validation loudly)

  const int* esrc = eidx;
  const int* edst = eidx + EE;

  // ---- weight prep ----
  k_prep<<<(s0 + 255) / 256, 256, 0, stream>>>(pa);

  // ---- SMILES branch ----
  k_gemm<float, 0><<<dim3(157, 3), 256, 0, stream>>>(smi_em, 100, Wb[0], bi_f, GIf, 300, 10000, 100, 300, 4, 19);
  k_gemm<float, 0><<<dim3(157, 3), 256, 0, stream>>>(smi_em, 100, Wb[1], bi_b, GIb, 300, 10000, 100, 300, 4, 19);
  k_gru<<<200, 320, 0, stream>>>(GIf, GIb, wh_f, wh_b, bh_f, bh_b, S);
  k_gemm<float, 1><<<dim3(157, 4), 256, 0, stream>>>(S, 200, Wb[2], fc_b1, ATT1, 512, 10000, 200, 512, 7, 32);
  k_gemm<float, 2><<<dim3(157, 2), 256, 0, stream>>>(ATT1, 512, Wb[3], fc_b2, ATT2, 256, 10000, 512, 256, 16, 16);
  k_soft<<<100, 256, 0, stream>>>(ATT2, WSUM);
  k_smi<<<100, 256, 0, stream>>>(S, WSUM, SMI0);
  k_gemm<float, 0><<<dim3(2, 4), 256, 0, stream>>>(SMI0, 200, Wb[4], lin_b1, SMIH, 512, 100, 200, 512, 7, 32);
  k_gemm<float, 0><<<dim3(2, 2), 256, 0, stream>>>(SMIH, 512, Wb[5], lin_b2, SMI, 256, 100, 512, 256, 16, 16);

  // ---- graph branch: CSR ----
  hipMemsetAsync(DEG, 0, (size_t)NN * 4, stream);
  k_hist<<<(EE + 255) / 256, 256, 0, stream>>>(edst, DEG);
  k_scan1<<<74, 256, 0, stream>>>(DEG, BSUM);
  k_scan2<<<1, 64, 0, stream>>>(BSUM, 74);
  k_scan3<<<74, 256, 0, stream>>>(DEG, BSUM, ROWP, CURS);
  k_fill<<<(EE + 255) / 256, 256, 0, stream>>>(esrc, edst, CURS, COLS);

  // ---- gin1 (fused both views) ----
  k_gather1<<<12500, 256, 0, stream>>>(x, mask, ROWP, COLS, AGG);
  k_gin1<<<2344, 256, 0, stream>>>(x, mask, AGG, Wb[6], conv1_b, H1);

  // ---- gin2 + pooling ----
  k_gather2<<<12500, 256, 0, stream>>>(H1, ROWP, COLS, SUM);
  k_gin2pool<<<dim3(800, 4), 256, 0, stream>>>(SUM, Wb[7], conv2_b, PP);
  k_poolred<<<(2 * 100 * 848 + 255) / 256, 256, 0, stream>>>(PP, POOL);

  // ---- fcg MLP (both views at once: M=200; writes x_g then y_g into d_out) ----
  k_gemm<float, 1><<<dim3(4, 8), 256, 0, stream>>>(POOL, 1696, Wb[8], fcg_b1, FCGH, 1024, 200, 1680, 1024, 53, 64);
  k_gemm<float, 0><<<dim3(4, 4), 256, 0, stream>>>(FCGH, 1024, Wb[9], fcg_b2, out + 100, 512, 200, 1024, 512, 32, 32);

  // ---- final head ----
  k_concat<<<300, 256, 0, stream>>>(out, SMI, FFIN);
  k_gemm<float, 1><<<dim3(2, 2), 256, 0, stream>>>(FFIN, 768, Wb[10], ff_b1, FFH, 256, 100, 768, 256, 24, 16);
  k_z<<<100, 256, 0, stream>>>(FFH, ff_w2, ff_b2, out);
}